// Round 1
// baseline (252.798 us; speedup 1.0000x reference)
//
#include <hip/hip_runtime.h>
#include <hip/hip_bf16.h>
#include <stdint.h>

#define B_ROWS 6144
#define N_ROWS 12288
#define DIM 256
#define NCLASS 512
#define NCHUNK 8
#define JCHUNK (N_ROWS / NCHUNK)   // 1536
#define NITER (JCHUNK / 64)        // 24
#define NITILE (N_ROWS / 128)      // 96
#define SCALE 14.426950408889634f  // log2(e)/0.1
#define LN2f 0.69314718055994531f

typedef float f32x4 __attribute__((ext_vector_type(4)));
typedef __bf16 bf16x8 __attribute__((ext_vector_type(8)));

// ---- workspace layout (bytes) ----
#define WS_EBF  ((size_t)0)
#define WS_S    ((size_t)(N_ROWS * DIM * 2))             // 6,291,456
#define WS_CNT  (WS_S + (size_t)NCLASS * DIM * 4)        // + 524,288
#define WS_PM   (WS_CNT + (size_t)NCLASS * 4)            // + 2,048
#define WS_PS   (WS_PM + (size_t)N_ROWS * NCHUNK * 4)    // + 393,216
#define WS_LOSS (WS_PS + (size_t)N_ROWS * NCHUNK * 4)    // + 393,216

__device__ inline float block_sum_256(float v, float* sbuf) {
#pragma unroll
  for (int off = 32; off; off >>= 1) v += __shfl_down(v, off);
  const int lane = threadIdx.x & 63;
  const int w = threadIdx.x >> 6;
  __syncthreads();
  if (lane == 0) sbuf[w] = v;
  __syncthreads();
  return sbuf[0] + sbuf[1] + sbuf[2] + sbuf[3];
}

// Kernel A: normalize rows, write bf16 embeddings, accumulate class sums/counts.
__global__ __launch_bounds__(256) void prep_kernel(const float* __restrict__ o1,
                                                   const float* __restrict__ o2,
                                                   const int* __restrict__ labels,
                                                   __bf16* __restrict__ ebf,
                                                   float* __restrict__ S,
                                                   int* __restrict__ cnt) {
  __shared__ float sbuf[4];
  const int row = blockIdx.x;
  const int d = threadIdx.x;
  const int li = (row < B_ROWS) ? row : row - B_ROWS;
  const float* src = (row < B_ROWS) ? (o1 + (size_t)row * DIM)
                                    : (o2 + (size_t)(row - B_ROWS) * DIM);
  const int lab = labels[li];
  const float x = src[d];
  const float ss = block_sum_256(x * x, sbuf);
  const float rn = 1.0f / fmaxf(sqrtf(ss), 1e-12f);
  const float e = x * rn;
  ebf[(size_t)row * DIM + d] = (__bf16)e;
  atomicAdd(&S[(size_t)lab * DIM + d], e);
  if (d == 0) atomicAdd(&cnt[lab], 1);
}

// Kernel B: streaming LSE over sim = E * E^T / T via MFMA bf16.
// Block: 4 waves, each wave owns 32 i-rows (2 fragment sets of 16).
// j loop: tiles of 64 rows staged into LDS in fragment order.
__global__ __launch_bounds__(256) void lse_kernel(const __bf16* __restrict__ ebf,
                                                  float* __restrict__ pm,
                                                  float* __restrict__ ps) {
  __shared__ __align__(16) char smem[32768];
  const int bid = blockIdx.x;
  const int itile = bid >> 3;  // 0..95
  const int chunk = bid & 7;   // 0..7
  const int i0 = itile * 128;
  const int jbase = chunk * JCHUNK;
  const int tid = threadIdx.x;
  const int lane = tid & 63;
  const int w = tid >> 6;
  const int l15 = lane & 15;
  const int g = lane >> 4;

  // A fragments in registers: rows i0 + w*32 + u*16 + (lane&15), k = kc*32 + g*8 + [0..7]
  bf16x8 a[2][8];
#pragma unroll
  for (int u = 0; u < 2; ++u) {
    const __bf16* arow = ebf + (size_t)(i0 + w * 32 + u * 16 + l15) * DIM + g * 8;
#pragma unroll
    for (int kc = 0; kc < 8; ++kc) a[u][kc] = *(const bf16x8*)(arow + kc * 32);
  }

  float m[2][4], s[2][4];
#pragma unroll
  for (int u = 0; u < 2; ++u)
#pragma unroll
    for (int r = 0; r < 4; ++r) { m[u][r] = -1e30f; s[u][r] = 0.0f; }

  const f32x4 zero = {0.0f, 0.0f, 0.0f, 0.0f};

  // prefetch first tile into registers
  uint4 stg[8];
#pragma unroll
  for (int rep = 0; rep < 8; ++rep) {
    const int f = rep * 4 + w, nt = f >> 3, kc = f & 7;
    stg[rep] = *(const uint4*)(ebf + (size_t)(jbase + nt * 16 + l15) * DIM + kc * 32 + g * 8);
  }

  for (int t = 0; t < NITER; ++t) {
    // write staged tile: fragment-ordered layout -> conflict-free b128 everywhere
#pragma unroll
    for (int rep = 0; rep < 8; ++rep)
      *(uint4*)(smem + (rep * 256 + w * 64 + lane) * 16) = stg[rep];
    __syncthreads();

    if (t + 1 < NITER) {
      const int j0 = jbase + (t + 1) * 64;
#pragma unroll
      for (int rep = 0; rep < 8; ++rep) {
        const int f = rep * 4 + w, nt = f >> 3, kc = f & 7;
        stg[rep] = *(const uint4*)(ebf + (size_t)(j0 + nt * 16 + l15) * DIM + kc * 32 + g * 8);
      }
    }

    f32x4 acc[2][4];
#pragma unroll
    for (int u = 0; u < 2; ++u)
#pragma unroll
      for (int nt = 0; nt < 4; ++nt) acc[u][nt] = zero;

#pragma unroll
    for (int kc = 0; kc < 8; ++kc) {
#pragma unroll
      for (int nt = 0; nt < 4; ++nt) {
        const bf16x8 b = *(const bf16x8*)(smem + ((nt * 8 + kc) * 64 + lane) * 16);
        acc[0][nt] = __builtin_amdgcn_mfma_f32_16x16x32_bf16(a[0][kc], b, acc[0][nt], 0, 0, 0);
        acc[1][nt] = __builtin_amdgcn_mfma_f32_16x16x32_bf16(a[1][kc], b, acc[1][nt], 0, 0, 0);
      }
    }

    // online LSE update in base-2; lane's acc[u][nt][r] is sim[i, j0+nt*16+(lane&15)]
#pragma unroll
    for (int u = 0; u < 2; ++u) {
#pragma unroll
      for (int r = 0; r < 4; ++r) {
        const float v0 = acc[u][0][r] * SCALE, v1 = acc[u][1][r] * SCALE;
        const float v2 = acc[u][2][r] * SCALE, v3 = acc[u][3][r] * SCALE;
        const float vmax = fmaxf(fmaxf(v0, v1), fmaxf(v2, v3));
        const float mn = fmaxf(m[u][r], vmax);
        s[u][r] = s[u][r] * __builtin_amdgcn_exp2f(m[u][r] - mn)
                + __builtin_amdgcn_exp2f(v0 - mn) + __builtin_amdgcn_exp2f(v1 - mn)
                + __builtin_amdgcn_exp2f(v2 - mn) + __builtin_amdgcn_exp2f(v3 - mn);
        m[u][r] = mn;
      }
    }
    __syncthreads();
  }

  // merge across the 16 lanes (same rows, different j columns)
#pragma unroll
  for (int off = 1; off < 16; off <<= 1) {
#pragma unroll
    for (int u = 0; u < 2; ++u)
#pragma unroll
      for (int r = 0; r < 4; ++r) {
        const float om = __shfl_xor(m[u][r], off);
        const float os = __shfl_xor(s[u][r], off);
        const float mn = fmaxf(m[u][r], om);
        s[u][r] = s[u][r] * __builtin_amdgcn_exp2f(m[u][r] - mn)
                + os * __builtin_amdgcn_exp2f(om - mn);
        m[u][r] = mn;
      }
  }

  if (l15 == 0) {
#pragma unroll
    for (int u = 0; u < 2; ++u)
#pragma unroll
      for (int r = 0; r < 4; ++r) {
        const int i = i0 + w * 32 + u * 16 + g * 4 + r;
        pm[(size_t)i * NCHUNK + chunk] = m[u][r];
        ps[(size_t)i * NCHUNK + chunk] = s[u][r];
      }
  }
}

// Kernel C: merge chunk partials -> LSE; exact fp32 positive term; per-row loss.
__global__ __launch_bounds__(256) void finish_kernel(const float* __restrict__ o1,
                                                     const float* __restrict__ o2,
                                                     const int* __restrict__ labels,
                                                     const float* __restrict__ S,
                                                     const int* __restrict__ cnt,
                                                     const float* __restrict__ pm,
                                                     const float* __restrict__ ps,
                                                     float* __restrict__ loss) {
  __shared__ float sbuf[4];
  const int row = blockIdx.x;
  const int d = threadIdx.x;
  const int li = (row < B_ROWS) ? row : row - B_ROWS;
  const float* src = (row < B_ROWS) ? (o1 + (size_t)row * DIM)
                                    : (o2 + (size_t)(row - B_ROWS) * DIM);
  const int lab = labels[li];
  const float x = src[d];
  const float ss = block_sum_256(x * x, sbuf);
  const float rn = 1.0f / fmaxf(sqrtf(ss), 1e-12f);
  const float e = x * rn;
  const float dot = block_sum_256(e * S[(size_t)lab * DIM + d], sbuf);
  if (d == 0) {
    float mm = -1e30f, sm = 0.0f;
#pragma unroll
    for (int c = 0; c < NCHUNK; ++c) {
      const float om = pm[(size_t)row * NCHUNK + c];
      const float os = ps[(size_t)row * NCHUNK + c];
      const float mn = fmaxf(mm, om);
      sm = sm * __builtin_amdgcn_exp2f(mm - mn) + os * __builtin_amdgcn_exp2f(om - mn);
      mm = mn;
    }
    const float lse = mm * LN2f + logf(sm);  // ln(sum_j exp(sim/T))
    loss[row] = lse - dot / (0.1f * (float)cnt[lab]);
  }
}

// Kernel D: deterministic mean.
__global__ __launch_bounds__(256) void mean_kernel(const float* __restrict__ loss,
                                                   float* __restrict__ out) {
  __shared__ float sbuf[4];
  float v = 0.0f;
  for (int i = threadIdx.x; i < N_ROWS; i += 256) v += loss[i];
  const float total = block_sum_256(v, sbuf);
  if (threadIdx.x == 0) out[0] = total * (1.0f / (float)N_ROWS);
}

extern "C" void kernel_launch(void* const* d_in, const int* in_sizes, int n_in,
                              void* d_out, int out_size, void* d_ws, size_t ws_size,
                              hipStream_t stream) {
  const float* o1 = (const float*)d_in[0];
  const float* o2 = (const float*)d_in[1];
  const int* labels = (const int*)d_in[2];
  char* ws = (char*)d_ws;
  __bf16* ebf = (__bf16*)(ws + WS_EBF);
  float* S = (float*)(ws + WS_S);
  int* cnt = (int*)(ws + WS_CNT);
  float* pm = (float*)(ws + WS_PM);
  float* ps = (float*)(ws + WS_PS);
  float* loss = (float*)(ws + WS_LOSS);

  hipMemsetAsync(S, 0, (size_t)NCLASS * DIM * 4 + (size_t)NCLASS * 4, stream);
  prep_kernel<<<N_ROWS, 256, 0, stream>>>(o1, o2, labels, ebf, S, cnt);
  lse_kernel<<<NITILE * NCHUNK, 256, 0, stream>>>(ebf, pm, ps);
  finish_kernel<<<N_ROWS, 256, 0, stream>>>(o1, o2, labels, S, cnt, pm, ps, loss);
  mean_kernel<<<1, 256, 0, stream>>>(loss, (float*)d_out);
}

// Round 3
// 121.184 us; speedup vs baseline: 2.0861x; 2.0861x over previous
//
#include <hip/hip_runtime.h>
#include <hip/hip_bf16.h>
#include <stdint.h>

#define B_ROWS 6144
#define N_ROWS 12288
#define DIM 256
#define NCLASS 512
#define NCHUNK 12
#define JCHUNK (N_ROWS / NCHUNK)   // 1024
#define JTILE 32
#define NITER (JCHUNK / JTILE)     // 32
#define MREP 3
#define ITILE 192                  // 4 waves * 48 rows
#define NITILE (N_ROWS / ITILE)    // 64
#define SCALE 14.426950408889634f  // log2(e)/0.1

typedef float f32x4 __attribute__((ext_vector_type(4)));
typedef __bf16 bf16x8 __attribute__((ext_vector_type(8)));

// ---- workspace layout (bytes) ----
// ebf: swizzled bf16 embeddings. Panel p = row>>4 (8192 B each):
//   byte(row,k) = p*8192 + (k>>5)*1024 + ((k>>3)&3)*256 + (row&15)*16 + (k&7)*2
// so a wave's fragment (16 rows, k-chunk kc, lane=g*16+r) is 1 KB contiguous.
#define WS_EBF  ((size_t)0)
#define WS_S    ((size_t)(N_ROWS * DIM * 2))             // 6,291,456
#define WS_CNT  (WS_S + (size_t)NCLASS * DIM * 4)        // + 524,288
#define WS_PS   (WS_CNT + (size_t)NCLASS * 4)            // + 2,048
#define WS_LOSS (WS_PS + (size_t)N_ROWS * NCHUNK * 4)    // + 589,824

__device__ inline void gload_lds16(const void* g, void* l) {
  __builtin_amdgcn_global_load_lds(
      (const __attribute__((address_space(1))) unsigned int*)g,
      (__attribute__((address_space(3))) unsigned int*)l, 16, 0, 0);
}

__device__ inline float block_sum_256(float v, float* sbuf) {
#pragma unroll
  for (int off = 32; off; off >>= 1) v += __shfl_down(v, off);
  const int lane = threadIdx.x & 63;
  const int w = threadIdx.x >> 6;
  __syncthreads();
  if (lane == 0) sbuf[w] = v;
  __syncthreads();
  return sbuf[0] + sbuf[1] + sbuf[2] + sbuf[3];
}

// Kernel A: normalize rows, write swizzled bf16 embeddings, class sums/counts.
__global__ __launch_bounds__(256) void prep_kernel(const float* __restrict__ o1,
                                                   const float* __restrict__ o2,
                                                   const int* __restrict__ labels,
                                                   __bf16* __restrict__ ebf,
                                                   float* __restrict__ S,
                                                   int* __restrict__ cnt) {
  __shared__ float sbuf[4];
  const int row = blockIdx.x;
  const int d = threadIdx.x;
  const int li = (row < B_ROWS) ? row : row - B_ROWS;
  const float* src = (row < B_ROWS) ? (o1 + (size_t)row * DIM)
                                    : (o2 + (size_t)(row - B_ROWS) * DIM);
  const int lab = labels[li];
  const float x = src[d];
  const float ss = block_sum_256(x * x, sbuf);
  const float rn = 1.0f / fmaxf(sqrtf(ss), 1e-12f);
  const float e = x * rn;
  // swizzled write (element index)
  const int p = row >> 4, r = row & 15;
  const int kc = d >> 5, g = (d >> 3) & 3, el = d & 7;
  ebf[(size_t)p * 4096 + kc * 512 + g * 128 + r * 8 + el] = (__bf16)e;
  atomicAdd(&S[(size_t)lab * DIM + d], e);
  if (d == 0) atomicAdd(&cnt[lab], 1);
}

// Kernel B: streaming sum of exp2(sim*SCALE) via MFMA bf16.
// 4 waves * 48 i-rows; j-tiles of 32 rows double-buffered in LDS via
// global_load_lds; no max tracking (sim bounded by 1).
// Sync structure = guide's verified T3 minimal recipe (m230):
//   STAGE(next) -> ds_read/MFMA(cur) -> vmcnt(0) -> barrier, 1 barrier/tile.
__global__ __launch_bounds__(256, 3) void lse_kernel(const __bf16* __restrict__ ebf,
                                                     float* __restrict__ ps) {
  __shared__ __align__(16) char smem[32768];  // 2 x 16KB buffers
  const int bid = blockIdx.x;
  const int itile = bid / NCHUNK;
  const int chunk = bid - itile * NCHUNK;
  const int i0 = itile * ITILE;
  const int tid = threadIdx.x;
  const int lane = tid & 63;
  const int w = tid >> 6;
  const char* const base = (const char*)ebf;

  // A fragments: wave w owns panels (i0>>4) + w*3 + m
  bf16x8 a[MREP][8];
  {
    const char* ap = base + (size_t)((i0 >> 4) + w * MREP) * 8192 + lane * 16;
#pragma unroll
    for (int m = 0; m < MREP; ++m)
#pragma unroll
      for (int kc = 0; kc < 8; ++kc)
        a[m][kc] = *(const bf16x8*)(ap + m * 8192 + kc * 1024);
  }

  f32x4 s[MREP];
#pragma unroll
  for (int m = 0; m < MREP; ++m) s[m] = (f32x4){0.0f, 0.0f, 0.0f, 0.0f};

  // staging pointer: frag f = i*4 + w of current j-panel-pair; +4096/issue
  const char* gsrc = base + (size_t)((chunk * JCHUNK) >> 4) * 8192 + w * 1024 + lane * 16;

  // prologue: stage tile 0 into buffer 0, drain, barrier
#pragma unroll
  for (int i = 0; i < 4; ++i) {
    gload_lds16(gsrc, smem + w * 1024 + i * 4096);
    gsrc += 4096;
  }
  asm volatile("s_waitcnt vmcnt(0)" ::: "memory");
  __syncthreads();
  __builtin_amdgcn_sched_barrier(0);

  for (int t = 0; t < NITER; ++t) {
    // 1) issue next-tile staging into the OTHER buffer (reads of that buffer
    //    finished before the barrier that ended iteration t-1)
    if (t + 1 < NITER) {
      char* ldst = smem + (((t + 1) & 1) << 14) + w * 1024;
#pragma unroll
      for (int i = 0; i < 4; ++i) {
        gload_lds16(gsrc, ldst + i * 4096);
        gsrc += 4096;
      }
    }

    // 2) ds_read current buffer + MFMA + exp2 accumulate
    const char* lb = smem + ((t & 1) << 14) + lane * 16;
    f32x4 acc[MREP][2];
#pragma unroll
    for (int m = 0; m < MREP; ++m) {
      acc[m][0] = (f32x4){0.0f, 0.0f, 0.0f, 0.0f};
      acc[m][1] = (f32x4){0.0f, 0.0f, 0.0f, 0.0f};
    }
#pragma unroll
    for (int kc = 0; kc < 8; ++kc) {
      const bf16x8 b0 = *(const bf16x8*)(lb + kc * 1024);
      const bf16x8 b1 = *(const bf16x8*)(lb + kc * 1024 + 8192);
#pragma unroll
      for (int m = 0; m < MREP; ++m) {
        acc[m][0] = __builtin_amdgcn_mfma_f32_16x16x32_bf16(a[m][kc], b0, acc[m][0], 0, 0, 0);
        acc[m][1] = __builtin_amdgcn_mfma_f32_16x16x32_bf16(a[m][kc], b1, acc[m][1], 0, 0, 0);
      }
    }
    // s += exp2(sim*SCALE): no max needed, sim in [-1,1]
#pragma unroll
    for (int m = 0; m < MREP; ++m)
#pragma unroll
      for (int r = 0; r < 4; ++r)
        s[m][r] += __builtin_amdgcn_exp2f(acc[m][0][r] * SCALE)
                 + __builtin_amdgcn_exp2f(acc[m][1][r] * SCALE);

    // 3) drain staging writes, then barrier: next tile fully resident and all
    //    waves' reads of the current buffer complete before anyone overwrites.
    __builtin_amdgcn_sched_barrier(0);
    asm volatile("s_waitcnt vmcnt(0)" ::: "memory");
    __syncthreads();
    __builtin_amdgcn_sched_barrier(0);
  }

  // merge across the 16 lanes sharing the same output rows (pure sum)
#pragma unroll
  for (int off = 1; off < 16; off <<= 1)
#pragma unroll
    for (int m = 0; m < MREP; ++m)
#pragma unroll
      for (int r = 0; r < 4; ++r)
        s[m][r] += __shfl_xor(s[m][r], off);

  if ((lane & 15) == 0) {
    const int g = lane >> 4;
#pragma unroll
    for (int m = 0; m < MREP; ++m)
#pragma unroll
      for (int r = 0; r < 4; ++r) {
        const int i = i0 + w * 48 + m * 16 + g * 4 + r;
        ps[(size_t)i * NCHUNK + chunk] = s[m][r];
      }
  }
}

// Kernel C: sum chunk partials -> LSE; exact fp32 positive term; per-row loss.
__global__ __launch_bounds__(256) void finish_kernel(const float* __restrict__ o1,
                                                     const float* __restrict__ o2,
                                                     const int* __restrict__ labels,
                                                     const float* __restrict__ S,
                                                     const int* __restrict__ cnt,
                                                     const float* __restrict__ ps,
                                                     float* __restrict__ loss) {
  __shared__ float sbuf[4];
  const int row = blockIdx.x;
  const int d = threadIdx.x;
  const int li = (row < B_ROWS) ? row : row - B_ROWS;
  const float* src = (row < B_ROWS) ? (o1 + (size_t)row * DIM)
                                    : (o2 + (size_t)(row - B_ROWS) * DIM);
  const int lab = labels[li];
  const float x = src[d];
  const float ss = block_sum_256(x * x, sbuf);
  const float rn = 1.0f / fmaxf(sqrtf(ss), 1e-12f);
  const float e = x * rn;
  const float dot = block_sum_256(e * S[(size_t)lab * DIM + d], sbuf);
  if (d == 0) {
    float sm = 0.0f;
#pragma unroll
    for (int c = 0; c < NCHUNK; ++c) sm += ps[(size_t)row * NCHUNK + c];
    const float lse = logf(sm);  // = ln(sum_j exp(sim/T))
    loss[row] = lse - dot / (0.1f * (float)cnt[lab]);
  }
}

// Kernel D: deterministic mean.
__global__ __launch_bounds__(256) void mean_kernel(const float* __restrict__ loss,
                                                   float* __restrict__ out) {
  __shared__ float sbuf[4];
  float v = 0.0f;
  for (int i = threadIdx.x; i < N_ROWS; i += 256) v += loss[i];
  const float total = block_sum_256(v, sbuf);
  if (threadIdx.x == 0) out[0] = total * (1.0f / (float)N_ROWS);
}

extern "C" void kernel_launch(void* const* d_in, const int* in_sizes, int n_in,
                              void* d_out, int out_size, void* d_ws, size_t ws_size,
                              hipStream_t stream) {
  const float* o1 = (const float*)d_in[0];
  const float* o2 = (const float*)d_in[1];
  const int* labels = (const int*)d_in[2];
  char* ws = (char*)d_ws;
  __bf16* ebf = (__bf16*)(ws + WS_EBF);
  float* S = (float*)(ws + WS_S);
  int* cnt = (int*)(ws + WS_CNT);
  float* ps = (float*)(ws + WS_PS);
  float* loss = (float*)(ws + WS_LOSS);

  hipMemsetAsync(S, 0, (size_t)NCLASS * DIM * 4 + (size_t)NCLASS * 4, stream);
  prep_kernel<<<N_ROWS, 256, 0, stream>>>(o1, o2, labels, ebf, S, cnt);
  lse_kernel<<<NITILE * NCHUNK, 256, 0, stream>>>(ebf, ps);
  finish_kernel<<<N_ROWS, 256, 0, stream>>>(o1, o2, labels, S, cnt, ps, loss);
  mean_kernel<<<1, 256, 0, stream>>>(loss, (float*)d_out);
}

// Round 4
// 114.675 us; speedup vs baseline: 2.2045x; 1.0568x over previous
//
#include <hip/hip_runtime.h>
#include <hip/hip_bf16.h>
#include <stdint.h>

#define B_ROWS 6144
#define N_ROWS 12288
#define DIM 256
#define NCHUNK 8
#define JCHUNK (N_ROWS / NCHUNK)   // 1536
#define JTILE 32
#define NITER (JCHUNK / JTILE)     // 48
#define MREP 3
#define ITILE 192                  // 4 waves * 48 rows
#define NITILE (N_ROWS / ITILE)    // 64  -> grid 512 = 2 blocks/CU exactly
#define SCALE 14.426950408889634f  // log2(e)/0.1

typedef float f32x4 __attribute__((ext_vector_type(4)));
typedef __bf16 bf16x8 __attribute__((ext_vector_type(8)));
typedef __bf16 bf16x4 __attribute__((ext_vector_type(4)));

// ---- workspace layout (bytes) ----
// ebf: swizzled bf16 embeddings. Panel p = row>>4 (8192 B each):
//   elem(row,k) = p*4096 + (k>>5)*512 + ((k>>3)&3)*128 + (row&15)*8 + (k&7)
#define WS_EBF  ((size_t)0)
#define WS_PS   ((size_t)(N_ROWS * DIM * 2))              // 6,291,456
#define WS_PP   (WS_PS + (size_t)N_ROWS * NCHUNK * 4)     // + 393,216
#define WS_PC   (WS_PP + (size_t)N_ROWS * NCHUNK * 4)     // + 393,216
#define WS_LOSS (WS_PC + (size_t)N_ROWS * NCHUNK * 4)     // + 393,216

__device__ inline void gload_lds16(const void* g, void* l) {
  __builtin_amdgcn_global_load_lds(
      (const __attribute__((address_space(1))) unsigned int*)g,
      (__attribute__((address_space(3))) unsigned int*)l, 16, 0, 0);
}

// Kernel A: normalize rows (wave per row), write swizzled bf16 embeddings.
// No atomics, no LDS, no block barrier.
__global__ __launch_bounds__(256) void prep_kernel(const float* __restrict__ o1,
                                                   const float* __restrict__ o2,
                                                   __bf16* __restrict__ ebf) {
  const int tid = threadIdx.x;
  const int lane = tid & 63;
  const int row = blockIdx.x * 4 + (tid >> 6);
  const float* src = (row < B_ROWS) ? (o1 + (size_t)row * DIM)
                                    : (o2 + (size_t)(row - B_ROWS) * DIM);
  const float4 v = ((const float4*)src)[lane];
  float ss = v.x * v.x + v.y * v.y + v.z * v.z + v.w * v.w;
#pragma unroll
  for (int off = 1; off < 64; off <<= 1) ss += __shfl_xor(ss, off);
  const float rn = 1.0f / fmaxf(sqrtf(ss), 1e-12f);
  bf16x4 h;
  h[0] = (__bf16)(v.x * rn); h[1] = (__bf16)(v.y * rn);
  h[2] = (__bf16)(v.z * rn); h[3] = (__bf16)(v.w * rn);
  // d = lane*4 .. lane*4+3 -> kc = lane>>3, g = (lane>>1)&3, el0 = (lane&1)*4
  const int p = row >> 4, r = row & 15;
  const size_t off = (size_t)p * 4096 + (lane >> 3) * 512 + ((lane >> 1) & 3) * 128
                   + r * 8 + (lane & 1) * 4;
  *(bf16x4*)(ebf + off) = h;
}

// Kernel B: streaming Sexp = sum_j exp(sim/T), pos = sum_{lab match} sim,
// cnt = #matches, all per i-row, via MFMA bf16 with a 3-buffer counted-vmcnt
// pipeline (T3+T4): STAGE(t+2) -> compute(t) -> lgkmcnt(0)+vmcnt(4) -> barrier.
__global__ __launch_bounds__(256, 2) void lse_kernel(const __bf16* __restrict__ ebf,
                                                     const long long* __restrict__ lab64,
                                                     float* __restrict__ ps,
                                                     float* __restrict__ pp,
                                                     float* __restrict__ pc) {
  __shared__ __align__(16) char smem[3 * 16384 + JCHUNK * 4];  // 55,296 B
  int* labsh = (int*)(smem + 3 * 16384);
  const int bid = blockIdx.x;
  const int itile = bid >> 3;  // 0..63
  const int chunk = bid & 7;   // 0..7
  const int i0 = itile * ITILE;
  const int jbase = chunk * JCHUNK;
  const int tid = threadIdx.x;
  const int lane = tid & 63;
  const int w = tid >> 6;
  const int l15 = lane & 15;
  const int g = lane >> 4;
  const char* const base = (const char*)ebf;

  // labels of this j-chunk -> LDS (truncate int64 -> int32, values < 512)
  for (int k = tid; k < JCHUNK; k += 256) {
    const int j = jbase + k;
    labsh[k] = (int)lab64[(j < B_ROWS) ? j : j - B_ROWS];
  }

  // A fragments: wave w owns panels (i0>>4) + w*3 + m
  bf16x8 a[MREP][8];
  {
    const char* ap = base + (size_t)((i0 >> 4) + w * MREP) * 8192 + lane * 16;
#pragma unroll
    for (int m = 0; m < MREP; ++m)
#pragma unroll
      for (int kc = 0; kc < 8; ++kc)
        a[m][kc] = *(const bf16x8*)(ap + m * 8192 + kc * 1024);
  }

  // labels of my 12 output rows: i = i0 + w*48 + m*16 + g*4 + r
  int labi[MREP][4];
#pragma unroll
  for (int m = 0; m < MREP; ++m)
#pragma unroll
    for (int r = 0; r < 4; ++r) {
      const int i = i0 + w * 48 + m * 16 + g * 4 + r;
      labi[m][r] = (int)lab64[(i < B_ROWS) ? i : i - B_ROWS];
    }

  float s[MREP][4], pos[MREP][4], pcn[MREP][4];
#pragma unroll
  for (int m = 0; m < MREP; ++m)
#pragma unroll
    for (int r = 0; r < 4; ++r) { s[m][r] = 0.0f; pos[m][r] = 0.0f; pcn[m][r] = 0.0f; }

  // staging: tile t = 16 KB = 16 frags of 1 KB; wave w stages frags q*4+w.
  const char* gsrc0 = base + (size_t)(jbase >> 4) * 8192 + w * 1024 + lane * 16;

  // prologue: stage tiles 0,1 into buffers 0,1; full drain; barrier.
#pragma unroll
  for (int q = 0; q < 4; ++q)
    gload_lds16(gsrc0 + q * 4096, smem + w * 1024 + q * 4096);
#pragma unroll
  for (int q = 0; q < 4; ++q)
    gload_lds16(gsrc0 + 16384 + q * 4096, smem + 16384 + w * 1024 + q * 4096);
  __syncthreads();  // implicit vmcnt(0) lgkmcnt(0): tiles 0,1 + labels resident

  int bsel = 0;  // buffer index t%3
  for (int t = 0; t < NITER; ++t) {
    // 1) stage tile t+2 into buffer (t+2)%3 (its readers finished at iter t-1)
    if (t + 2 < NITER) {
      const char* gs = gsrc0 + (size_t)(t + 2) * 16384;
      char* ldst = smem + ((bsel + 2) % 3) * 16384 + w * 1024;
#pragma unroll
      for (int q = 0; q < 4; ++q) gload_lds16(gs + q * 4096, ldst + q * 4096);
    }

    // 2) compute tile t from buffer bsel
    const char* lb = smem + bsel * 16384 + lane * 16;
    f32x4 acc[MREP][2];
#pragma unroll
    for (int m = 0; m < MREP; ++m) {
      acc[m][0] = (f32x4){0.0f, 0.0f, 0.0f, 0.0f};
      acc[m][1] = (f32x4){0.0f, 0.0f, 0.0f, 0.0f};
    }
#pragma unroll
    for (int kc = 0; kc < 8; ++kc) {
      const bf16x8 b0 = *(const bf16x8*)(lb + kc * 1024);
      const bf16x8 b1 = *(const bf16x8*)(lb + kc * 1024 + 8192);
#pragma unroll
      for (int m = 0; m < MREP; ++m) {
        acc[m][0] = __builtin_amdgcn_mfma_f32_16x16x32_bf16(a[m][kc], b0, acc[m][0], 0, 0, 0);
        acc[m][1] = __builtin_amdgcn_mfma_f32_16x16x32_bf16(a[m][kc], b1, acc[m][1], 0, 0, 0);
      }
    }
    // epilogue: j-col for (nt,l15) = jbase + t*32 + nt*16 + l15
    const int labj0 = labsh[t * 32 + l15];
    const int labj1 = labsh[t * 32 + 16 + l15];
#pragma unroll
    for (int m = 0; m < MREP; ++m)
#pragma unroll
      for (int r = 0; r < 4; ++r) {
        const float v0 = acc[m][0][r], v1 = acc[m][1][r];
        s[m][r] += __builtin_amdgcn_exp2f(v0 * SCALE)
                 + __builtin_amdgcn_exp2f(v1 * SCALE);
        const bool p0 = (labj0 == labi[m][r]), p1 = (labj1 == labi[m][r]);
        pos[m][r] += (p0 ? v0 : 0.0f) + (p1 ? v1 : 0.0f);
        pcn[m][r] += (p0 ? 1.0f : 0.0f) + (p1 ? 1.0f : 0.0f);
      }

    // 3) counted drain + raw barrier (no vmcnt(0) in steady state)
    __builtin_amdgcn_sched_barrier(0);
    asm volatile("s_waitcnt lgkmcnt(0)" ::: "memory");
    if (t + 2 < NITER) {
      asm volatile("s_waitcnt vmcnt(4)" ::: "memory");  // stage(t+1) landed, t+2 in flight
    } else {
      asm volatile("s_waitcnt vmcnt(0)" ::: "memory");  // tail
    }
    __builtin_amdgcn_sched_barrier(0);
    __builtin_amdgcn_s_barrier();
    __builtin_amdgcn_sched_barrier(0);

    bsel = (bsel + 1) % 3;
  }

  // merge across the 16 lanes sharing the same output rows (pure sums)
#pragma unroll
  for (int off = 1; off < 16; off <<= 1)
#pragma unroll
    for (int m = 0; m < MREP; ++m)
#pragma unroll
      for (int r = 0; r < 4; ++r) {
        s[m][r] += __shfl_xor(s[m][r], off);
        pos[m][r] += __shfl_xor(pos[m][r], off);
        pcn[m][r] += __shfl_xor(pcn[m][r], off);
      }

  if (l15 == 0) {
#pragma unroll
    for (int m = 0; m < MREP; ++m)
#pragma unroll
      for (int r = 0; r < 4; ++r) {
        const int i = i0 + w * 48 + m * 16 + g * 4 + r;
        ps[(size_t)i * NCHUNK + chunk] = s[m][r];
        pp[(size_t)i * NCHUNK + chunk] = pos[m][r];
        pc[(size_t)i * NCHUNK + chunk] = pcn[m][r];
      }
  }
}

// Kernel C: merge chunk partials -> per-row loss. One thread per row.
__global__ __launch_bounds__(256) void finish_kernel(const float* __restrict__ ps,
                                                     const float* __restrict__ pp,
                                                     const float* __restrict__ pc,
                                                     float* __restrict__ loss) {
  const int row = blockIdx.x * 256 + threadIdx.x;
  const float4 s0 = ((const float4*)(ps + (size_t)row * 8))[0];
  const float4 s1 = ((const float4*)(ps + (size_t)row * 8))[1];
  const float4 p0 = ((const float4*)(pp + (size_t)row * 8))[0];
  const float4 p1 = ((const float4*)(pp + (size_t)row * 8))[1];
  const float4 c0 = ((const float4*)(pc + (size_t)row * 8))[0];
  const float4 c1 = ((const float4*)(pc + (size_t)row * 8))[1];
  const float sm = (s0.x + s0.y + s0.z + s0.w) + (s1.x + s1.y + s1.z + s1.w);
  const float pm = (p0.x + p0.y + p0.z + p0.w) + (p1.x + p1.y + p1.z + p1.w);
  const float cm = (c0.x + c0.y + c0.z + c0.w) + (c1.x + c1.y + c1.z + c1.w);
  loss[row] = logf(sm) - pm / (0.1f * cm);
}

// Kernel D: deterministic mean.
__global__ __launch_bounds__(256) void mean_kernel(const float* __restrict__ loss,
                                                   float* __restrict__ out) {
  __shared__ float sbuf[4];
  float v = 0.0f;
  for (int i = threadIdx.x; i < N_ROWS; i += 256) v += loss[i];
#pragma unroll
  for (int off = 32; off; off >>= 1) v += __shfl_down(v, off);
  const int lane = threadIdx.x & 63;
  const int w = threadIdx.x >> 6;
  if (lane == 0) sbuf[w] = v;
  __syncthreads();
  if (threadIdx.x == 0)
    out[0] = (sbuf[0] + sbuf[1] + sbuf[2] + sbuf[3]) * (1.0f / (float)N_ROWS);
}

extern "C" void kernel_launch(void* const* d_in, const int* in_sizes, int n_in,
                              void* d_out, int out_size, void* d_ws, size_t ws_size,
                              hipStream_t stream) {
  const float* o1 = (const float*)d_in[0];
  const float* o2 = (const float*)d_in[1];
  const long long* labels = (const long long*)d_in[2];
  char* ws = (char*)d_ws;
  __bf16* ebf = (__bf16*)(ws + WS_EBF);
  float* ps = (float*)(ws + WS_PS);
  float* pp = (float*)(ws + WS_PP);
  float* pc = (float*)(ws + WS_PC);
  float* loss = (float*)(ws + WS_LOSS);

  prep_kernel<<<N_ROWS / 4, 256, 0, stream>>>(o1, o2, ebf);
  lse_kernel<<<NITILE * NCHUNK, 256, 0, stream>>>(ebf, labels, ps, pp, pc);
  finish_kernel<<<N_ROWS / 256, 256, 0, stream>>>(ps, pp, pc, loss);
  mean_kernel<<<1, 256, 0, stream>>>(loss, (float*)d_out);
}